// Round 5
// baseline (6167.423 us; speedup 1.0000x reference)
//
#include <hip/hip_runtime.h>

// ---------------- problem constants ----------------
constexpr int N_ = 1024;   // ITEM_SIZE
constexpr int B_ = 64;     // BATCH
constexpr int T_ = 64;     // SEQ
constexpr int CAP = 96;    // cidx capacity per node (max in-degree ~61 incl self-loop)
constexpr size_t OUT0 = (size_t)B_ * T_ * N_;   // outs f32, then h [B][N][32] f32

// ROUND-18: cooperative-persistent design replaced by per-step kernel pairs.
//  - No grid barrier, no sc-atomics, no partial publishing: kernel boundaries order
//    phase P/A' (k_pa) vs GRU (k_b) and step t vs t+1.
//  - h state lives in out+OUT0 ([b][n][32] f32 — exactly the final-h layout, and the
//    harness's memset gives h0 = 0 for free). ws holds only gi + tables = 13.75 MB,
//    below the 14.8 MB proven in round-17.
//  - k_pa: 128 blocks (2/batch) x 512 thr, FC weights staged in LDS once per block,
//    FULL neighbor h-sums from global (L2-resident), gi written bf16 to global.
//  - k_b: 1024 blocks (16/batch, 64 rows) x 256 thr, launch_bounds(256,2) so the
//    ~190-VGPR register-resident GRU never spills (round-16 lesson).

// ---------------- workspace layout (float offsets) — total 13.75 MB ----------------
constexpr size_t WINTo  = 0;        // w_in^T  [j][i] 128*64 = 8192
constexpr size_t WOUTTo = 8192;     // w_out^T                 8192
constexpr size_t WIHTo  = 16384;    // w_ih^T  [j][g]  64*96 = 6144   (0..22528 staged as one blob)
constexpr size_t WHHo   = 22528;    // w_hh row-major          3072
constexpr size_t WFCo   = 25600;    // 32
constexpr size_t BINo   = 25632;    // 64
constexpr size_t BOUTo  = 25696;    // 64
constexpr size_t BIHo   = 25760;    // 96
constexpr size_t BHHo   = 25856;    // 96
constexpr size_t BFCo   = 25952;    // 16 (1 used)
constexpr size_t INAo   = 25968;    // 1024
constexpr size_t OUTAo  = 26992;    // 1024
constexpr size_t CCNTo  = 28016;    // 1024 int (in-degree per node)
constexpr size_t DTFo   = 29040;    // 16 (dtype flag int)
constexpr size_t IEMo   = 29056;    // item_emb f32 32768
constexpr size_t REMo   = 61824;    // resp_emb f32 65536
constexpr size_t SUMEMBo= 127360;   // sum of item_emb over in-neighbors: 1024*32
constexpr size_t OMASKo = 160128;   // u64[1024][16]: omask[v] bit j = adj[v][j] (32768 f)
constexpr size_t CIDXo  = 192896;   // 1024*96 int (CSC col lists, ascending) = 98304
constexpr size_t GIo    = 291200;   // gi bf16 [64][1024][96] = 6,291,456 us = 3,145,728 f
// end = 3,436,928 floats = 13,747,712 B  (< 14,808,576 B proven in round-17)

// ---------------- k_pa LDS ----------------
constexpr int PA_WSTG   = 22528;                 // winT+woutT+wihT staged as one blob
constexpr int PA_FSTG   = 8 * 128;               // per-wave fea staging
constexpr int PA_LDSF   = PA_WSTG + PA_FSTG;     // 23552 floats
constexpr int PA_LDSB   = PA_LDSF * 4;           // 94,208 B (< 160 KB/CU; 1 block/CU)

// ---------------- helpers ----------------
__device__ __forceinline__ float bf2f(unsigned short u) {
    union { unsigned int i; float f; } x; x.i = ((unsigned int)u) << 16; return x.f;
}
__device__ __forceinline__ unsigned short f2bf(float f) {
    union { float f; unsigned int u; } x; x.f = f;
    unsigned int u = x.u;
    return (unsigned short)((u + 0x7fffu + ((u >> 16) & 1u)) >> 16);  // RNE
}
__device__ __forceinline__ float sigm(float x) { return 1.f / (1.f + __expf(-x)); }
__device__ __forceinline__ float tanhx(float x) {
    x = fminf(15.f, fmaxf(-15.f, x));
    float e = __expf(2.f * x);
    return (e - 1.f) / (e + 1.f);
}
__device__ __forceinline__ float ldg_any(const void* p, int i, int isbf) {
    return isbf ? bf2f(((const unsigned short*)p)[i]) : ((const float*)p)[i];
}

// ---------------- prep: detect input float dtype from adj bit patterns ----------------
__global__ void k_detect(const unsigned int* __restrict__ adjw, float* __restrict__ ws)
{
    __shared__ int f;
    if (threadIdx.x == 0) f = 0;
    __syncthreads();
    int local = 0;
    for (int i = threadIdx.x; i < 524288; i += blockDim.x) {
        unsigned int w = adjw[i];
        if ((w & 0xFFFFu) == 0x3F80u) local = 1;
    }
    if (local) atomicOr(&f, 1);
    __syncthreads();
    if (threadIdx.x == 0) ((int*)(ws + DTFo))[0] = f;
}

// ---------------- prep: convert/pack weights -> f32 ----------------
__global__ void k_convert(const void* __restrict__ w_in,  const void* __restrict__ b_in,
                          const void* __restrict__ w_out, const void* __restrict__ b_out,
                          const void* __restrict__ in_a,  const void* __restrict__ out_a,
                          const void* __restrict__ w_ih,  const void* __restrict__ w_hh,
                          const void* __restrict__ b_ih,  const void* __restrict__ b_hh,
                          const void* __restrict__ w_fc,  const void* __restrict__ b_fc,
                          const void* __restrict__ item_emb, const void* __restrict__ resp_emb,
                          float* __restrict__ ws)
{
    const int isbf = ((const int*)(ws + DTFo))[0];
    const int tg  = blockIdx.x * blockDim.x + threadIdx.x;
    const int tot = gridDim.x * blockDim.x;
    for (int f = tg; f < 8192; f += tot) {
        int i = f & 63, j = f >> 6;
        ws[WINTo + f]  = ldg_any(w_in , i * 128 + j, isbf);
        ws[WOUTTo + f] = ldg_any(w_out, i * 128 + j, isbf);
    }
    for (int f = tg; f < 6144; f += tot) {
        int g = f % 96, j = f / 96;
        ws[WIHTo + f] = ldg_any(w_ih, g * 64 + j, isbf);
    }
    for (int f = tg; f < 3072; f += tot) ws[WHHo + f] = ldg_any(w_hh, f, isbf);
    for (int f = tg; f < 32;   f += tot) ws[WFCo + f] = ldg_any(w_fc, f, isbf);
    for (int f = tg; f < 64;   f += tot) { ws[BINo + f] = ldg_any(b_in, f, isbf); ws[BOUTo + f] = ldg_any(b_out, f, isbf); }
    for (int f = tg; f < 96;   f += tot) { ws[BIHo + f] = ldg_any(b_ih, f, isbf); ws[BHHo + f] = ldg_any(b_hh, f, isbf); }
    if (tg == 0) ws[BFCo] = ldg_any(b_fc, 0, isbf);
    for (int f = tg; f < 1024; f += tot) { ws[INAo + f] = ldg_any(in_a, f, isbf); ws[OUTAo + f] = ldg_any(out_a, f, isbf); }
    for (int f = tg; f < 32768; f += tot) ws[IEMo + f] = ldg_any(item_emb, f, isbf);
    for (int f = tg; f < 65536; f += tot) ws[REMo + f] = ldg_any(resp_emb, f, isbf);
}

// ---------------- prep: build CSC adjacency ----------------
__global__ void k_csc(const void* __restrict__ adj, float* __restrict__ ws)
{
    const int isbf = ((const int*)(ws + DTFo))[0];
    const int v = blockIdx.x;
    const int lane = threadIdx.x;
    int* ccnt = (int*)(ws + CCNTo);
    int* cidx = (int*)(ws + CIDXo);
    int cnt = 0;
    for (int ch = 0; ch < 16; ++ch) {
        int row = ch * 64 + lane;
        bool nz;
        if (isbf) nz = (((const unsigned short*)adj)[row * 1024 + v] != 0);
        else      nz = (((const float*)adj)[row * 1024 + v] != 0.f);
        unsigned long long m = __ballot(nz);
        int pos = cnt + __popcll(m & ((1ull << lane) - 1ull));
        if (nz && pos < CAP) cidx[v * CAP + pos] = row;
        cnt += __popcll(m);
    }
    if (lane == 0) ccnt[v] = (cnt > CAP) ? CAP : cnt;
}

// ---------------- prep: out-neighbor bitmasks + static embedding sums ----------------
__global__ void k_emb(const void* __restrict__ adj, float* __restrict__ ws)
{
    const int isbf = ((const int*)(ws + DTFo))[0];
    const int v = blockIdx.x;
    const int lane = threadIdx.x;
    unsigned long long* om = (unsigned long long*)(ws + OMASKo);
    for (int w = 0; w < 16; ++w) {
        int col = w * 64 + lane;
        bool nz;
        if (isbf) nz = (((const unsigned short*)adj)[v * 1024 + col] != 0);
        else      nz = (((const float*)adj)[v * 1024 + col] != 0.f);
        unsigned long long m = __ballot(nz);
        if (lane == 0) om[v * 16 + w] = m;
    }
    const int cnt = ((const int*)(ws + CCNTo))[v];
    const int* cl = (const int*)(ws + CIDXo) + v * CAP;
    float acc = 0.f;
    for (int k = 0; k < cnt; ++k) {
        int u = cl[k];
        if (lane < 32) acc += ws[IEMo + u * 32 + lane];
    }
    if (lane < 32) ws[SUMEMBo + v * 32 + lane] = acc;
}

// ---------------- prep: init gi = b_ih (bf16) for all [64][1024] rows ----------------
__global__ void k_init(float* __restrict__ ws)
{
    const int tg  = blockIdx.x * blockDim.x + threadIdx.x;
    const int tot = gridDim.x * blockDim.x;
    unsigned short* gi = (unsigned short*)(ws + GIo);
    for (size_t i = tg; i < (size_t)64 * 1024 * 96; i += tot)
        gi[i] = f2bf(ws[BIHo + (i % 96)]);
}

// ---------------- per-step: phase P + A' (aggregate + FC + gi for dst nodes) ----------------
// 128 blocks = 2 per batch, 512 thr. Weights staged in LDS once; full neighbor h-sums
// read from global h (L2-resident); gi written bf16 to global. No atomics, no barriers.
__global__ __launch_bounds__(512, 1) void k_pa(
    const int* __restrict__ item_ids, const int* __restrict__ responses,
    float* __restrict__ ws, const float* __restrict__ out, int t)
{
    extern __shared__ float sm[];
    float* winT  = sm;            // [8192]
    float* woutT = sm + 8192;     // [8192]
    float* wihT  = sm + 16384;    // [6144]
    float* fea_stage = sm + PA_WSTG;  // [8][128]

    const int tid  = threadIdx.x;
    const int lane = tid & 63;
    const int wave = tid >> 6;         // 0..7
    const int b    = blockIdx.x >> 1;
    const int half = blockIdx.x & 1;

    const int item = item_ids[b * T_ + t];
    const int resp = responses[b * T_ + t];
    const int* __restrict__ ccnt = (const int*)(ws + CCNTo);
    const int ndst0 = ccnt[item];
    const int ndst  = (ndst0 > 64) ? 64 : ndst0;
    if (half * 8 >= ndst) return;      // whole block has no dsts

    // stage FC weights (one contiguous 90KB blob) as float4
    {
        const float4* src = (const float4*)ws;       // WINTo == 0
        float4* dst = (float4*)sm;
        for (int i = tid; i < PA_WSTG / 4; i += 512) dst[i] = src[i];
    }
    __syncthreads();

    const float* __restrict__ bin_f = ws + BINo;
    const float* __restrict__ bout_f= ws + BOUTo;
    const float* __restrict__ bih_f = ws + BIHo;
    const float* __restrict__ ina_f = ws + INAo;
    const float* __restrict__ outa_f= ws + OUTAo;
    const float* __restrict__ iem   = ws + IEMo;
    const float* __restrict__ rem   = ws + REMo;
    const float* __restrict__ semb  = ws + SUMEMBo;
    const int* __restrict__ cidx = (const int*)(ws + CIDXo);
    const unsigned long long* __restrict__ omk = (const unsigned long long*)(ws + OMASKo);
    const float* __restrict__ hb = out + OUT0 + (size_t)b * 32768;   // h state [1024][32]
    unsigned short* __restrict__ giB = (unsigned short*)(ws + GIo) + (size_t)b * 98304;

    const float remv = (lane >= 32) ? rem[resp * 32 + (lane - 32)] : 0.f;
    float* fstage = fea_stage + wave * 128;

    for (int i = half * 8 + wave; i < ndst; i += 16) {
        const int v = cidx[item * CAP + i];
        float own, agg;
        if (lane < 32) {
            own = hb[v * 32 + lane];
            // FULL in-neighbor h-sum (no partials: kernel boundary gives us全 h)
            float acc = 0.f;
            const int cnt = ccnt[v];
            const int* cl = cidx + v * CAP;
            for (int k = 0; k < cnt; ++k)
                acc += hb[cl[k] * 32 + lane];
            agg = acc;
        } else {
            const int j = lane - 32;
            own = (v == item) ? remv : iem[v * 32 + j];
            const bool hasitem = (omk[item * 16 + (v >> 6)] >> (v & 63)) & 1ull;
            agg = semb[v * 32 + j] + (hasitem ? (remv - iem[item * 32 + j]) : 0.f);
        }
        fstage[lane]      = own;
        fstage[64 + lane] = agg;
        float ain = 0.f, aout = 0.f;
        const float4* f4p = (const float4*)fstage;
        #pragma unroll 8
        for (int c = 0; c < 32; ++c) {
            const float4 f = f4p[c];
            ain  += f.x * winT [(4*c+0)*64 + lane] + f.y * winT [(4*c+1)*64 + lane]
                  + f.z * winT [(4*c+2)*64 + lane] + f.w * winT [(4*c+3)*64 + lane];
            aout += f.x * woutT[(4*c+0)*64 + lane] + f.y * woutT[(4*c+1)*64 + lane]
                  + f.z * woutT[(4*c+2)*64 + lane] + f.w * woutT[(4*c+3)*64 + lane];
        }
        ain  += bin_f[lane];
        aout += bout_f[lane];
        const float dstv = outa_f[v] * aout + ina_f[v] * ain;
        fstage[lane] = dstv;   // reuse own slot (wave-coherent LDS, proven pattern)
        float g0 = bih_f[lane];
        float g1 = (lane < 32) ? bih_f[64 + lane] : 0.f;
        const float4* d4p = (const float4*)fstage;
        #pragma unroll 8
        for (int c = 0; c < 16; ++c) {
            const float4 dv = d4p[c];
            g0 += dv.x * wihT[(4*c+0)*96 + lane] + dv.y * wihT[(4*c+1)*96 + lane]
                + dv.z * wihT[(4*c+2)*96 + lane] + dv.w * wihT[(4*c+3)*96 + lane];
            if (lane < 32) {
                g1 += dv.x * wihT[(4*c+0)*96 + 64 + lane] + dv.y * wihT[(4*c+1)*96 + 64 + lane]
                    + dv.z * wihT[(4*c+2)*96 + 64 + lane] + dv.w * wihT[(4*c+3)*96 + 64 + lane];
            }
        }
        unsigned short* gp = giB + (size_t)v * 96;
        gp[lane] = f2bf(g0);
        if (lane < 32) gp[64 + lane] = f2bf(g1);
    }
}

// ---------------- per-step: phase B (GRU on all rows) ----------------
// 1024 blocks = 16 per batch (64 rows each), 256 thr = 8 groups of 32 lanes,
// 8 rows serial per group. h read/written in out+OUT0 (in place: only this block
// touches its rows this step). launch_bounds(256,2) -> VGPR cap 256, no spill.
__global__ __launch_bounds__(256, 2) void k_b(
    float* __restrict__ ws, float* __restrict__ out, int t)
{
    __shared__ float outst[64];
    const int tid  = threadIdx.x;
    const int s    = tid & 31;
    const int grp  = tid >> 5;          // 0..7
    const int b    = blockIdx.x >> 4;
    const int sl   = blockIdx.x & 15;
    const int base = sl * 64;

    const float* __restrict__ whh   = ws + WHHo;
    const float* __restrict__ bhh_f = ws + BHHo;
    float* __restrict__ hb = out + OUT0 + (size_t)b * 32768;
    const unsigned short* __restrict__ giB = (const unsigned short*)(ws + GIo) + (size_t)b * 98304;

    float wr[32], wz[32], wn[32];
    #pragma unroll
    for (int j = 0; j < 32; ++j) {
        wr[j] = whh[s * 32 + j];
        wz[j] = whh[(32 + s) * 32 + j];
        wn[j] = whh[(64 + s) * 32 + j];
    }
    const float bhr = bhh_f[s], bhz = bhh_f[32 + s], bhn = bhh_f[64 + s];
    const float wfcs = ws[WFCo + s];
    const float bfc  = ws[BFCo];

    int nl = base + grp * 8;
    const unsigned short* r0 = giB + (size_t)nl * 96;
    unsigned short cS = r0[s], c32 = r0[32 + s], c64 = r0[64 + s];
    const float4* hrow = (const float4*)(hb + nl * 32);
    float4 ch[8];
    #pragma unroll
    for (int q = 0; q < 8; ++q) ch[q] = hrow[q];
    float h_own = hb[nl * 32 + s];

    for (int i = 0; i < 8; ++i, ++nl) {
        unsigned short nS = 0, n32 = 0, n64 = 0;
        float4 nh[8];
        float nh_own = 0.f;
        if (i < 7) {
            const unsigned short* r1 = giB + (size_t)(nl + 1) * 96;
            nS  = r1[s];
            n32 = r1[32 + s];
            n64 = r1[64 + s];
            const float4* hnx = (const float4*)(hb + (nl + 1) * 32);
            #pragma unroll
            for (int q = 0; q < 8; ++q) nh[q] = hnx[q];
            nh_own = hb[(nl + 1) * 32 + s];
        }
        float ar = bhr, az = bhz, an = bhn;
        const float* hf = (const float*)ch;
        #pragma unroll
        for (int j = 0; j < 32; ++j) {
            const float hv = hf[j];
            ar += wr[j] * hv; az += wz[j] * hv; an += wn[j] * hv;
        }
        const float gir = bf2f(cS), giz = bf2f(c32), gin = bf2f(c64);
        const float rg = sigm(gir + ar);
        const float zg = sigm(giz + az);
        const float ng = tanhx(gin + rg * an);
        const float hv2 = (1.f - zg) * ng + zg * h_own;
        hb[nl * 32 + s] = hv2;                 // in-place h update (own rows only)
        float red = hv2 * wfcs;
        red += __shfl_xor(red, 16); red += __shfl_xor(red, 8);
        red += __shfl_xor(red, 4);  red += __shfl_xor(red, 2);
        red += __shfl_xor(red, 1);
        if (s == 0) outst[nl - base] = sigm(red + bfc);
        cS = nS; c32 = n32; c64 = n64; h_own = nh_own;
        #pragma unroll
        for (int q = 0; q < 8; ++q) ch[q] = nh[q];
    }
    __syncthreads();
    if (tid < 64)
        __builtin_nontemporal_store(outst[tid],
            out + (size_t)b * 65536 + (size_t)t * 1024 + base + tid);
}

extern "C" void kernel_launch(void* const* d_in, const int* in_sizes, int n_in,
                              void* d_out, int out_size, void* d_ws, size_t ws_size,
                              hipStream_t stream)
{
    (void)in_sizes; (void)n_in; (void)out_size; (void)ws_size;
    const int* item_ids  = (const int*)d_in[0];
    const int* responses = (const int*)d_in[1];
    const void* adj      = d_in[2];
    const void* item_emb = d_in[3];
    const void* resp_emb = d_in[4];
    const void* w_in  = d_in[5];
    const void* b_in  = d_in[6];
    const void* w_out = d_in[7];
    const void* b_out = d_in[8];
    const void* in_a  = d_in[9];
    const void* out_a = d_in[10];
    const void* w_ih  = d_in[11];
    const void* w_hh  = d_in[12];
    const void* b_ih  = d_in[13];
    const void* b_hh  = d_in[14];
    const void* w_fc  = d_in[15];
    const void* b_fc  = d_in[16];
    float* ws = (float*)d_ws;
    float* out = (float*)d_out;

    (void)hipFuncSetAttribute((const void*)k_pa,
                              hipFuncAttributeMaxDynamicSharedMemorySize, PA_LDSB);

    k_detect<<<dim3(1), dim3(1024), 0, stream>>>((const unsigned int*)adj, ws);
    k_convert<<<dim3(64), dim3(256), 0, stream>>>(w_in, b_in, w_out, b_out, in_a, out_a,
                                                  w_ih, w_hh, b_ih, b_hh, w_fc, b_fc,
                                                  item_emb, resp_emb, ws);
    k_csc<<<dim3(1024), dim3(64), 0, stream>>>(adj, ws);
    k_emb<<<dim3(1024), dim3(64), 0, stream>>>(adj, ws);
    k_init<<<dim3(512), dim3(256), 0, stream>>>(ws);

    for (int t = 0; t < T_; ++t) {
        k_pa<<<dim3(128), dim3(512), PA_LDSB, stream>>>(item_ids, responses, ws, out, t);
        k_b<<<dim3(1024), dim3(256), 0, stream>>>(ws, out, t);
    }
}

// Round 6
// 2494.995 us; speedup vs baseline: 2.4719x; 2.4719x over previous
//
#include <hip/hip_runtime.h>

// ---------------- problem constants ----------------
constexpr int N_ = 1024;   // ITEM_SIZE
constexpr int B_ = 64;     // BATCH
constexpr int T_ = 64;     // SEQ
constexpr int CAP = 96;    // cidx capacity per node (max in-degree ~61 incl self-loop)
constexpr int CAPD = 64;   // dst capacity per step (ndst = indeg(item) <= ~61)
constexpr size_t OUT0 = (size_t)B_ * T_ * N_;   // outs f32, then h [B][N][32] f32

// ROUND-19: 8-subs-per-batch persistent kernel via PLAIN (non-cooperative) launch.
//  - R14/15 proved the cooperative API rejects 512-block grids; hardware capacity math
//    says 2 blocks/CU fits (2x43.8KB LDS <= 160KB, 8 waves/CU, VGPR<=256 enforced).
//    Persistent spin-barrier blocks only need co-residency: worst-case packing is
//    3/CU -> capacity 768 >= 512 -> every block placed -> no deadlock.
//  - Host queries occupancy; if < 2 blocks/CU it falls back to the PROVEN 4-sub
//    shape (256 blocks x 512 thr) also launched non-cooperatively (capacity 256/256).
//  - Both shapes share one templated kernel <NSUB, NTHR>.
//  - Micro-fixes vs R13: staged coalesced out-flush (kills ~150MB 64B-sector write
//    amplification), 128B-strided barrier counters, multi-block k_detect (220->~15us).

// ---------------- workspace layout (float offsets) — total 9.59 MB ----------------
constexpr size_t WINTo  = 0;        // w_in^T  [j][i] 128*64 = 8192
constexpr size_t WOUTTo = 8192;     // w_out^T                 8192
constexpr size_t WIHTo  = 16384;    // w_ih^T  [j][g]  64*96 = 6144
constexpr size_t WHHo   = 22528;    // w_hh row-major          3072
constexpr size_t WFCo   = 25600;    // 32
constexpr size_t BINo   = 25632;    // 64
constexpr size_t BOUTo  = 25696;    // 64
constexpr size_t BIHo   = 25760;    // 96
constexpr size_t BHHo   = 25856;    // 96
constexpr size_t BFCo   = 25952;    // 16 (1 used)
constexpr size_t INAo   = 25968;    // 1024
constexpr size_t OUTAo  = 26992;    // 1024
constexpr size_t CCNTo  = 28016;    // 1024 int (in-degree per node)
constexpr size_t DTFo   = 29040;    // 16 (dtype flag int)
constexpr size_t IEMo   = 29056;    // item_emb f32 32768
constexpr size_t REMo   = 61824;    // resp_emb f32 65536
constexpr size_t SUMEMBo= 127360;   // sum of item_emb over in-neighbors: 1024*32
constexpr size_t QCNTo  = 160128;   // [1024][8] ints: octant boundaries (rows < 128*(o+1))
constexpr size_t OMASKo = 168320;   // u64[1024][16]: omask[v] bit j = adj[v][j] (32768 f)
constexpr size_t CIDXo  = 201088;   // 1024*96 int (CSC col lists, ascending) = 98304
constexpr size_t PARTo  = 299392;   // partials f32 [par2][b64][CAPD][8*32] = 2,097,152
constexpr size_t BARo   = 2396544;  // 64 counters, padded to 32-int (128B) stride = 2048
// end = 2,398,592 floats = 9,594,368 B (= round-15 layout; within proven budget)

// ---------------- helpers ----------------
__device__ __forceinline__ float bf2f(unsigned short u) {
    union { unsigned int i; float f; } x; x.i = ((unsigned int)u) << 16; return x.f;
}
__device__ __forceinline__ unsigned short f2bf(float f) {
    union { float f; unsigned int u; } x; x.f = f;
    unsigned int u = x.u;
    return (unsigned short)((u + 0x7fffu + ((u >> 16) & 1u)) >> 16);  // RNE
}
__device__ __forceinline__ float sigm(float x) { return 1.f / (1.f + __expf(-x)); }
__device__ __forceinline__ float tanhx(float x) {
    x = fminf(15.f, fmaxf(-15.f, x));
    float e = __expf(2.f * x);
    return (e - 1.f) / (e + 1.f);
}
__device__ __forceinline__ float ldg_any(const void* p, int i, int isbf) {
    return isbf ? bf2f(((const unsigned short*)p)[i]) : ((const float*)p)[i];
}

// Coherent-point (sc-flagged) 4B accessors: per-address agent coherence, no cache
// maintenance. Visibility once vmcnt retires (i.e., after __syncthreads). Proven R13.
__device__ __forceinline__ void cstore(float* p, float v) {
    __hip_atomic_store((unsigned int*)p, __float_as_uint(v),
                       __ATOMIC_RELAXED, __HIP_MEMORY_SCOPE_AGENT);
}
__device__ __forceinline__ float cload(const float* p) {
    return __uint_as_float(__hip_atomic_load((const unsigned int*)p,
                       __ATOMIC_RELAXED, __HIP_MEMORY_SCOPE_AGENT));
}

// NSUB-block per-batch epoch barrier (fence-free; payload is sc-coherent).
template<int NSUB>
__device__ __forceinline__ void barN(int* c, int& ep, int tid) {
    __syncthreads();
    if (tid == 0) {
        __hip_atomic_fetch_add(c, 1, __ATOMIC_RELAXED, __HIP_MEMORY_SCOPE_AGENT);
        const int target = NSUB * (++ep);
        while (__hip_atomic_load(c, __ATOMIC_RELAXED, __HIP_MEMORY_SCOPE_AGENT) < target)
            __builtin_amdgcn_s_sleep(1);
    } else {
        ++ep;
    }
    __syncthreads();
}

// ---------------- prep: zero dtype flag + barrier counters ----------------
__global__ void k_zero(float* __restrict__ ws)
{
    const int tg = threadIdx.x;
    if (tg == 0) ((int*)(ws + DTFo))[0] = 0;
    for (int i = tg; i < 2048; i += 256) ((int*)(ws + BARo))[i] = 0;
}

// ---------------- prep: detect input float dtype (multi-block; was 220us serial) ----------------
__global__ void k_detect(const unsigned int* __restrict__ adjw, float* __restrict__ ws)
{
    const int tg  = blockIdx.x * blockDim.x + threadIdx.x;
    const int tot = gridDim.x * blockDim.x;
    int local = 0;
    for (int i = tg; i < 524288; i += tot) {
        unsigned int w = adjw[i];
        if ((w & 0xFFFFu) == 0x3F80u) local = 1;
    }
    if (__ballot(local) && (threadIdx.x & 63) == 0)
        atomicOr((int*)(ws + DTFo), 1);
}

// ---------------- prep: convert/pack weights -> f32 ----------------
__global__ void k_convert(const void* __restrict__ w_in,  const void* __restrict__ b_in,
                          const void* __restrict__ w_out, const void* __restrict__ b_out,
                          const void* __restrict__ in_a,  const void* __restrict__ out_a,
                          const void* __restrict__ w_ih,  const void* __restrict__ w_hh,
                          const void* __restrict__ b_ih,  const void* __restrict__ b_hh,
                          const void* __restrict__ w_fc,  const void* __restrict__ b_fc,
                          const void* __restrict__ item_emb, const void* __restrict__ resp_emb,
                          float* __restrict__ ws)
{
    const int isbf = ((const int*)(ws + DTFo))[0];
    const int tg  = blockIdx.x * blockDim.x + threadIdx.x;
    const int tot = gridDim.x * blockDim.x;
    for (int f = tg; f < 8192; f += tot) {
        int i = f & 63, j = f >> 6;
        ws[WINTo + f]  = ldg_any(w_in , i * 128 + j, isbf);
        ws[WOUTTo + f] = ldg_any(w_out, i * 128 + j, isbf);
    }
    for (int f = tg; f < 6144; f += tot) {
        int g = f % 96, j = f / 96;
        ws[WIHTo + f] = ldg_any(w_ih, g * 64 + j, isbf);
    }
    for (int f = tg; f < 3072; f += tot) ws[WHHo + f] = ldg_any(w_hh, f, isbf);
    for (int f = tg; f < 32;   f += tot) ws[WFCo + f] = ldg_any(w_fc, f, isbf);
    for (int f = tg; f < 64;   f += tot) { ws[BINo + f] = ldg_any(b_in, f, isbf); ws[BOUTo + f] = ldg_any(b_out, f, isbf); }
    for (int f = tg; f < 96;   f += tot) { ws[BIHo + f] = ldg_any(b_ih, f, isbf); ws[BHHo + f] = ldg_any(b_hh, f, isbf); }
    if (tg == 0) ws[BFCo] = ldg_any(b_fc, 0, isbf);
    for (int f = tg; f < 1024; f += tot) { ws[INAo + f] = ldg_any(in_a, f, isbf); ws[OUTAo + f] = ldg_any(out_a, f, isbf); }
    for (int f = tg; f < 32768; f += tot) ws[IEMo + f] = ldg_any(item_emb, f, isbf);
    for (int f = tg; f < 65536; f += tot) ws[REMo + f] = ldg_any(resp_emb, f, isbf);
}

// ---------------- prep: build CSC adjacency + octant boundaries ----------------
__global__ void k_csc(const void* __restrict__ adj, float* __restrict__ ws)
{
    const int isbf = ((const int*)(ws + DTFo))[0];
    const int v = blockIdx.x;
    const int lane = threadIdx.x;
    int* ccnt = (int*)(ws + CCNTo);
    int* cidx = (int*)(ws + CIDXo);
    int* qcb  = (int*)(ws + QCNTo);   // [1024][8]
    int cnt = 0;
    int bnd[7];
    for (int ch = 0; ch < 16; ++ch) {
        int row = ch * 64 + lane;
        bool nz;
        if (isbf) nz = (((const unsigned short*)adj)[row * 1024 + v] != 0);
        else      nz = (((const float*)adj)[row * 1024 + v] != 0.f);
        unsigned long long m = __ballot(nz);
        int pos = cnt + __popcll(m & ((1ull << lane) - 1ull));
        if (nz && pos < CAP) cidx[v * CAP + pos] = row;
        cnt += __popcll(m);
        if ((ch & 1) && ch < 15) bnd[ch >> 1] = (cnt > CAP) ? CAP : cnt;  // rows < 128*(k+1)
    }
    if (lane == 0) {
        ccnt[v] = (cnt > CAP) ? CAP : cnt;
        #pragma unroll
        for (int o = 0; o < 7; ++o) qcb[v * 8 + o] = bnd[o];
        qcb[v * 8 + 7] = 0;
    }
}

// ---------------- prep: out-neighbor bitmasks + static embedding sums ----------------
__global__ void k_emb(const void* __restrict__ adj, float* __restrict__ ws)
{
    const int isbf = ((const int*)(ws + DTFo))[0];
    const int v = blockIdx.x;
    const int lane = threadIdx.x;
    unsigned long long* om = (unsigned long long*)(ws + OMASKo);
    for (int w = 0; w < 16; ++w) {
        int col = w * 64 + lane;
        bool nz;
        if (isbf) nz = (((const unsigned short*)adj)[v * 1024 + col] != 0);
        else      nz = (((const float*)adj)[v * 1024 + col] != 0.f);
        unsigned long long m = __ballot(nz);
        if (lane == 0) om[v * 16 + w] = m;
    }
    const int cnt = ((const int*)(ws + CCNTo))[v];
    const int* cl = (const int*)(ws + CIDXo) + v * CAP;
    float acc = 0.f;
    for (int k = 0; k < cnt; ++k) {
        int u = cl[k];
        if (lane < 32) acc += ws[IEMo + u * 32 + lane];
    }
    if (lane < 32) ws[SUMEMBo + v * 32 + lane] = acc;
}

// ---------------- main: NSUB blocks per batch, persistent, PLAIN launch ----------------
// Block owns nodes [sub*OWN, sub*OWN+OWN): h f32 + gi bf16 in LDS for the whole kernel.
// Cross-block traffic per step = sc-coherent partial h-sums (parity dbuf) + 1 barN.
template<int NSUB, int NTHR>
__global__ __launch_bounds__(NTHR, 2) void gkt_main(
    const int* __restrict__ item_ids, const int* __restrict__ responses,
    float* ws, float* __restrict__ out)
{
    constexpr int OWN   = N_ / NSUB;    // 128 (8-sub) or 256 (4-sub)
    constexpr int WAVES = NTHR / 64;    // 4 or 8
    constexpr int QSTEP = 8 / NSUB;     // octant-table stride: 1 or 2
    extern __shared__ float smem[];
    float* h_lds = smem;                                        // [OWN][32]
    unsigned short* gi16 = (unsigned short*)(smem + OWN * 32);  // [OWN][96] bf16
    float* fea_stage = smem + OWN * 32 + OWN * 48;              // [WAVES][128]
    int* dlist = (int*)(smem + OWN * 32 + OWN * 48 + WAVES * 128);       // [64]
    float* out_stage = smem + OWN * 32 + OWN * 48 + WAVES * 128 + 64;    // [OWN]

    const int tid  = threadIdx.x;
    const int lane = tid & 63;
    const int wave = tid >> 6;
    const int bid  = blockIdx.x;
    const int sub  = bid >> 6;                            // 0..NSUB-1
    const int b    = ((bid & 63) + (sub << 3)) & 63;      // scrambled: co-resident pair
    const int base = sub * OWN;                           //   (bid,bid+256) = diff batch
    const int s    = lane & 31;
    const int gsel = (lane >> 5) & 1;

    int* barc = (int*)(ws + BARo) + b * 32;               // 128B-strided counters
    const float* __restrict__ winT  = ws + WINTo;
    const float* __restrict__ woutT = ws + WOUTTo;
    const float* __restrict__ wihT  = ws + WIHTo;
    const float* __restrict__ whh   = ws + WHHo;
    const float* __restrict__ bin_f = ws + BINo;
    const float* __restrict__ bout_f= ws + BOUTo;
    const float* __restrict__ bih_f = ws + BIHo;
    const float* __restrict__ bhh_f = ws + BHHo;
    const float* __restrict__ ina_f = ws + INAo;
    const float* __restrict__ outa_f= ws + OUTAo;
    const float* __restrict__ iem   = ws + IEMo;
    const float* __restrict__ rem   = ws + REMo;
    const float* __restrict__ semb  = ws + SUMEMBo;
    const int* __restrict__ ccnt = (const int*)(ws + CCNTo);
    const int* __restrict__ cidx = (const int*)(ws + CIDXo);
    const int* __restrict__ qcb  = (const int*)(ws + QCNTo);
    const unsigned long long* __restrict__ omk = (const unsigned long long*)(ws + OMASKo);

    // init LDS: h = 0, gi = b_ih (bf16)
    for (int i = tid; i < OWN * 32; i += NTHR) h_lds[i] = 0.f;
    for (int i = tid; i < OWN * 96; i += NTHR) gi16[i] = f2bf(bih_f[i % 96]);

    // register-stationary GRU recurrent weights for this lane's state index s
    float wr[32], wz[32], wn[32];
    #pragma unroll
    for (int j = 0; j < 32; ++j) {
        wr[j] = whh[s * 32 + j];
        wz[j] = whh[(32 + s) * 32 + j];
        wn[j] = whh[(64 + s) * 32 + j];
    }
    const float bhr = bhh_f[s], bhz = bhh_f[32 + s], bhn = bhh_f[64 + s];
    const float wfcs = ws[WFCo + s];
    const float bfc  = ws[BFCo];
    __syncthreads();

    int ep = 0;
    const int gid = wave * 2 + gsel;   // group id; owns rows [gid*16, gid*16+16)

    for (int t = 0; t < T_; ++t) {
        const int item = item_ids[b * T_ + t];
        const int resp = responses[b * T_ + t];
        const int ndst0 = ccnt[item];
        const int ndst  = (ndst0 > CAPD) ? CAPD : ndst0;   // data max ~61 < 64
        if (tid < ndst) dlist[tid] = cidx[item * CAP + tid];
        __syncthreads();
        const float remv = (lane >= 32) ? rem[resp * 32 + (lane - 32)] : 0.f;

        float* Pbuf = ws + PARTo + ((size_t)(t & 1) * 64 + b) * (CAPD * 256);  // [i][256]

        // ---- phase P: partial h-sums over own OWN rows, for every dst i ----
        for (int i = wave; i < ndst; i += WAVES) {
            const int v = dlist[i];
            const int k0 = (sub == 0) ? 0 : qcb[v * 8 + sub * QSTEP - 1];
            const int k1 = (sub == NSUB - 1) ? ccnt[v] : qcb[v * 8 + (sub + 1) * QSTEP - 1];
            float acc = 0.f;
            for (int k = k0; k < k1; ++k) {
                const int ul = cidx[v * CAP + k] - base;
                if (lane < 32) acc += h_lds[ul * 32 + lane];
            }
            if (lane < 32) cstore(Pbuf + i * 256 + sub * 32 + lane, acc);
        }
        barN<NSUB>(barc, ep, tid);   // publish partials (the ONLY cross-block sync/step)

        // ---- phase A': FC + gi for dst nodes in OWN range ----
        float* fstage = fea_stage + wave * 128;
        for (int i = wave; i < ndst; i += WAVES) {
            const int v = dlist[i];
            if ((v / OWN) != sub) continue;          // wave-uniform skip
            const int vl = v & (OWN - 1);
            float own, agg;
            if (lane < 32) {
                own = h_lds[vl * 32 + lane];
                const float* pp = Pbuf + i * 256;
                agg = 0.f;
                #pragma unroll
                for (int q = 0; q < NSUB; ++q) agg += cload(pp + q * 32 + lane);
            } else {
                const int j = lane - 32;
                own = (v == item) ? remv : iem[v * 32 + j];
                const bool hasitem = (omk[item * 16 + (v >> 6)] >> (v & 63)) & 1ull;
                agg = semb[v * 32 + j] + (hasitem ? (remv - iem[item * 32 + j]) : 0.f);
            }
            fstage[lane]      = own;
            fstage[64 + lane] = agg;
            float ain = 0.f, aout = 0.f;
            const float4* f4p = (const float4*)fstage;
            #pragma unroll 8
            for (int c = 0; c < 32; ++c) {
                const float4 f = f4p[c];
                ain  += f.x * winT [(4*c+0)*64 + lane] + f.y * winT [(4*c+1)*64 + lane]
                      + f.z * winT [(4*c+2)*64 + lane] + f.w * winT [(4*c+3)*64 + lane];
                aout += f.x * woutT[(4*c+0)*64 + lane] + f.y * woutT[(4*c+1)*64 + lane]
                      + f.z * woutT[(4*c+2)*64 + lane] + f.w * woutT[(4*c+3)*64 + lane];
            }
            ain  += bin_f[lane];
            aout += bout_f[lane];
            const float dstv = outa_f[v] * aout + ina_f[v] * ain;
            fstage[lane] = dstv;   // reuse own slot (same-wave LDS order; proven R16)
            float g0 = bih_f[lane];
            float g1 = (lane < 32) ? bih_f[64 + lane] : 0.f;
            const float4* d4p = (const float4*)fstage;
            #pragma unroll 8
            for (int c = 0; c < 16; ++c) {
                const float4 dv = d4p[c];
                g0 += dv.x * wihT[(4*c+0)*96 + lane] + dv.y * wihT[(4*c+1)*96 + lane]
                    + dv.z * wihT[(4*c+2)*96 + lane] + dv.w * wihT[(4*c+3)*96 + lane];
                if (lane < 32) {
                    g1 += dv.x * wihT[(4*c+0)*96 + 64 + lane] + dv.y * wihT[(4*c+1)*96 + 64 + lane]
                        + dv.z * wihT[(4*c+2)*96 + 64 + lane] + dv.w * wihT[(4*c+3)*96 + 64 + lane];
                }
            }
            gi16[vl * 96 + lane] = f2bf(g0);
            if (lane < 32) gi16[vl * 96 + 64 + lane] = f2bf(g1);
        }
        __syncthreads();   // gi_lds visible to phase B

        // ---- phase B: GRU on own rows [gid*16, gid*16+16), all LDS ----
        {
            int nl = gid * 16;
            unsigned short cS = gi16[nl * 96 + s], c32 = gi16[nl * 96 + 32 + s], c64 = gi16[nl * 96 + 64 + s];
            const float4* hrow = (const float4*)(h_lds + nl * 32);
            float4 ch[8];
            #pragma unroll
            for (int q = 0; q < 8; ++q) ch[q] = hrow[q];
            float h_own = h_lds[nl * 32 + s];

            for (int i = 0; i < 16; ++i, ++nl) {
                unsigned short nS = 0, n32 = 0, n64 = 0;
                float4 nh[8];
                float nh_own = 0.f;
                if (i < 15) {
                    nS  = gi16[(nl + 1) * 96 + s];
                    n32 = gi16[(nl + 1) * 96 + 32 + s];
                    n64 = gi16[(nl + 1) * 96 + 64 + s];
                    const float4* hnx = (const float4*)(h_lds + (nl + 1) * 32);
                    #pragma unroll
                    for (int q = 0; q < 8; ++q) nh[q] = hnx[q];
                    nh_own = h_lds[(nl + 1) * 32 + s];
                }
                float ar = bhr, az = bhz, an = bhn;
                const float* hf = (const float*)ch;
                #pragma unroll
                for (int j = 0; j < 32; ++j) {
                    const float hv = hf[j];
                    ar += wr[j] * hv; az += wz[j] * hv; an += wn[j] * hv;
                }
                const float gir = bf2f(cS), giz = bf2f(c32), gin = bf2f(c64);
                const float rg = sigm(gir + ar);
                const float zg = sigm(giz + az);
                const float ng = tanhx(gin + rg * an);
                const float hv2 = (1.f - zg) * ng + zg * h_own;
                h_lds[nl * 32 + s] = hv2;
                float red = hv2 * wfcs;
                red += __shfl_xor(red, 16); red += __shfl_xor(red, 8);
                red += __shfl_xor(red, 4);  red += __shfl_xor(red, 2);
                red += __shfl_xor(red, 1);
                if (s == 0) out_stage[nl] = sigm(red + bfc);   // staged; flush below
                if (t == T_ - 1) {
                    const int n = base + nl;
                    __builtin_nontemporal_store(hv2,
                                out + OUT0 + (size_t)b * 32768 + (size_t)n * 32 + s);
                }
                cS = nS; c32 = n32; c64 = n64; h_own = nh_own;
                #pragma unroll
                for (int q = 0; q < 8; ++q) ch[q] = nh[q];
            }
        }
        __syncthreads();   // h_lds + out_stage complete (also guards next-step phase P)

        // coalesced out flush: one contiguous OWN*4B store per block-step
        if (tid < OWN)
            __builtin_nontemporal_store(out_stage[tid],
                out + (size_t)b * 65536 + (size_t)t * 1024 + base + tid);
    }
}

extern "C" void kernel_launch(void* const* d_in, const int* in_sizes, int n_in,
                              void* d_out, int out_size, void* d_ws, size_t ws_size,
                              hipStream_t stream)
{
    (void)in_sizes; (void)n_in; (void)out_size; (void)ws_size;
    const int* item_ids  = (const int*)d_in[0];
    const int* responses = (const int*)d_in[1];
    const void* adj      = d_in[2];
    const void* item_emb = d_in[3];
    const void* resp_emb = d_in[4];
    const void* w_in  = d_in[5];
    const void* b_in  = d_in[6];
    const void* w_out = d_in[7];
    const void* b_out = d_in[8];
    const void* in_a  = d_in[9];
    const void* out_a = d_in[10];
    const void* w_ih  = d_in[11];
    const void* w_hh  = d_in[12];
    const void* b_ih  = d_in[13];
    const void* b_hh  = d_in[14];
    const void* w_fc  = d_in[15];
    const void* b_fc  = d_in[16];
    float* ws = (float*)d_ws;
    float* out = (float*)d_out;

    // LDS sizes: floats = OWN*80 + WAVES*128 + 64 + OWN
    constexpr int LDS8B = (128 * 80 + 4 * 128 + 64 + 128) * 4;   // 43,776 B (2 blocks/CU)
    constexpr int LDS4B = (256 * 80 + 8 * 128 + 64 + 256) * 4;   // 87,296 B (1 block/CU)

    (void)hipFuncSetAttribute((const void*)&gkt_main<8, 256>,
                              hipFuncAttributeMaxDynamicSharedMemorySize, LDS8B);
    (void)hipFuncSetAttribute((const void*)&gkt_main<4, 512>,
                              hipFuncAttributeMaxDynamicSharedMemorySize, LDS4B);

    k_zero<<<dim3(1), dim3(256), 0, stream>>>(ws);
    k_detect<<<dim3(256), dim3(256), 0, stream>>>((const unsigned int*)adj, ws);
    k_convert<<<dim3(64), dim3(256), 0, stream>>>(w_in, b_in, w_out, b_out, in_a, out_a,
                                                  w_ih, w_hh, b_ih, b_hh, w_fc, b_fc,
                                                  item_emb, resp_emb, ws);
    k_csc<<<dim3(1024), dim3(64), 0, stream>>>(adj, ws);
    k_emb<<<dim3(1024), dim3(64), 0, stream>>>(adj, ws);

    // Pick shape by queried occupancy: 8-sub needs 2 blocks/CU co-residency.
    int occ = 0;
    (void)hipOccupancyMaxActiveBlocksPerMultiprocessor(
        &occ, (const void*)&gkt_main<8, 256>, 256, (size_t)LDS8B);
    if (occ >= 2) {
        gkt_main<8, 256><<<dim3(512), dim3(256), LDS8B, stream>>>(item_ids, responses, ws, out);
    } else {
        gkt_main<4, 512><<<dim3(256), dim3(512), LDS4B, stream>>>(item_ids, responses, ws, out);
    }
}